// Round 6
// baseline (807.100 us; speedup 1.0000x reference)
//
#include <hip/hip_runtime.h>
#include <hip/hip_bf16.h>
#include <stdint.h>

#define D_MODEL 768
#define NHEAD 12
#define DK 64
#define SQ 4096
#define BATCH 2
#define MROWS (BATCH*SQ)                 // 8192
#define WELEMS (D_MODEL*D_MODEL)         // 589824
#define XELEMS ((size_t)MROWS*D_MODEL)   // 6291456
#define TENS_ELEMS ((size_t)BATCH*NHEAD*SQ*DK) // 6291456

// scale folded into q projection: (1/sqrt(dk)) * log2(e)
#define QSCALE 0.1803368801111244f

typedef __attribute__((ext_vector_type(8))) unsigned short u16x8;
typedef __attribute__((ext_vector_type(4))) unsigned short u16x4;
typedef __attribute__((ext_vector_type(4))) unsigned int   u32x4;
typedef __attribute__((ext_vector_type(8))) __bf16 bf16x8;
typedef __attribute__((ext_vector_type(4))) float f32x4;
typedef __attribute__((ext_vector_type(16))) float f32x16;

__device__ __forceinline__ unsigned short f2bfu(float f){
    uint32_t u = __float_as_uint(f);
    return (unsigned short)((u + 0x7fffu + ((u >> 16) & 1u)) >> 16);
}

__device__ __forceinline__ bf16x8 load_bf8(const unsigned short* p){
    u16x8 t = *reinterpret_cast<const u16x8*>(p);
    return __builtin_bit_cast(bf16x8, t);
}

__device__ __forceinline__ unsigned cvtpk(float lo, float hi){
    unsigned r;
    asm("v_cvt_pk_bf16_f32 %0, %1, %2" : "=v"(r) : "v"(lo), "v"(hi));
    return r;
}

// raw v_exp_f32: computes 2^x in one trans-pipe instruction (no libm expansion)
__device__ __forceinline__ float exp2_hw(float x){
    float r;
    asm("v_exp_f32 %0, %1" : "=v"(r) : "v"(x));
    return r;
}

__device__ __forceinline__ f32x16 zero16(){
    f32x16 z;
    #pragma unroll
    for (int i = 0; i < 16; ++i) z[i] = 0.f;
    return z;
}

// ---- weight convert: 4x (768x768) f32 -> bf16 packed [Wq|Wk|Wv|Wo] ----
__global__ __launch_bounds__(256) void wconv_kernel(const float* w0, const float* w1,
                                                    const float* w2, const float* w3,
                                                    unsigned short* dst){
    const float* src = (blockIdx.y == 0) ? w0 : (blockIdx.y == 1) ? w1 :
                       (blockIdx.y == 2) ? w2 : w3;
    unsigned short* d = dst + (size_t)blockIdx.y * WELEMS;
    int i = (blockIdx.x * blockDim.x + threadIdx.x) * 4;
    if (i < WELEMS){
        float4 v = *reinterpret_cast<const float4*>(src + i);
        u16x4 o;
        o[0]=f2bfu(v.x); o[1]=f2bfu(v.y); o[2]=f2bfu(v.z); o[3]=f2bfu(v.w);
        *reinterpret_cast<u16x4*>(d + i) = o;
    }
}

// ---- activation convert: 8192x768 f32 -> bf16 ----
__global__ __launch_bounds__(256) void xconv_kernel(const float* src, unsigned short* dst){
    size_t i = ((size_t)blockIdx.x * blockDim.x + threadIdx.x) * 4;
    float4 v = *reinterpret_cast<const float4*>(src + i);
    u16x4 o;
    o[0]=f2bfu(v.x); o[1]=f2bfu(v.y); o[2]=f2bfu(v.z); o[3]=f2bfu(v.w);
    *reinterpret_cast<u16x4*>(dst + i) = o;
}

// ---- Y = X @ W^T + b (scaled). A bf16 8192x768. Block 64x64 (4 waves), wave 16x64. ----
// grid (128,12) = 1536 blocks -> 6 waves/SIMD occupancy.
// MODE 0: out bf16 (B,H,S,dk) q (oscale=QSCALE)
// MODE 1: out bf16 (B,H,S,dk) k
// MODE 2: out bf16 (B,H,dk,S) v transposed
// MODE 3: out f32 row-major 8192x768
template<int MODE>
__global__ __launch_bounds__(256) void gemm_kernel(const unsigned short* A, const unsigned short* Wb,
                                                   const float* bias, float oscale, void* out_){
    const int wave = threadIdx.x >> 6, lane = threadIdx.x & 63;
    const int g = lane >> 4, c16 = lane & 15;
    const int m0 = blockIdx.x * 64 + wave * 16;
    const int n0 = blockIdx.y * 64;
    f32x4 acc[4];
    #pragma unroll
    for (int c = 0; c < 4; ++c) acc[c] = f32x4{0.f,0.f,0.f,0.f};
    const unsigned short* ap = A  + (size_t)(m0 + c16) * D_MODEL + g * 8;
    const unsigned short* bp = Wb + (size_t)(n0 + c16) * D_MODEL + g * 8;
    #pragma unroll 4
    for (int kc = 0; kc < D_MODEL; kc += 32){
        bf16x8 af = load_bf8(ap + kc);
        #pragma unroll
        for (int c = 0; c < 4; ++c){
            bf16x8 bfr = load_bf8(bp + (size_t)(c*16) * D_MODEL + kc);
            acc[c] = __builtin_amdgcn_mfma_f32_16x16x32_bf16(af, bfr, acc[c], 0, 0, 0);
        }
    }
    #pragma unroll
    for (int c = 0; c < 4; ++c){
        const int n = n0 + c*16 + c16;
        const float bv = bias[n];
        #pragma unroll
        for (int r = 0; r < 4; ++r){
            const int mrow = m0 + g*4 + r;
            const float v = (acc[c][r] + bv) * oscale;
            if constexpr (MODE == 3){
                ((float*)out_)[(size_t)mrow * D_MODEL + n] = v;
            } else {
                const int b = mrow >> 12, s = mrow & 4095;
                const int h = n >> 6, d = n & 63;
                unsigned short* o = (unsigned short*)out_;
                if constexpr (MODE == 2){
                    o[((size_t)(b*NHEAD + h)*DK + d)*SQ + s] = f2bfu(v);
                } else {
                    o[((size_t)(b*NHEAD + h)*SQ + s)*DK + d] = f2bfu(v);
                }
            }
        }
    }
}

// ---- Flash attention, swapped-QK^T 32x32, softmax fully in-register ----
// q (pre-scaled), k: (B,H,S,64) bf16. vt: (B,H,64,S) bf16. Out att: (B,S,768) bf16.
// Block = 4 waves x 32 q rows. KVBLK = 64. No max-subtraction (scores bounded).
__global__ __launch_bounds__(256) void attn_kernel(const unsigned short* q, const unsigned short* k,
                                                   const unsigned short* vt, unsigned short* att){
    const int lane = threadIdx.x & 63;
    const int wave = threadIdx.x >> 6;
    const int c32 = lane & 31, hi = lane >> 5;
    const int bh = blockIdx.y;
    const int b = bh / NHEAD, h = bh % NHEAD;
    const int q0 = blockIdx.x * 128 + wave * 32;
    const unsigned short* qb = q + ((size_t)bh * SQ + q0) * DK;

    // hoisted per-lane base pointers; inner offsets are compile-time immediates
    const unsigned short* kp = k  + (size_t)bh * SQ * DK + (size_t)c32 * DK + hi * 8;
    const unsigned short* vp = vt + (size_t)bh * DK * SQ + (size_t)c32 * SQ + hi * 8;

    bf16x8 qf[4];
    #pragma unroll
    for (int ks = 0; ks < 4; ++ks)
        qf[ks] = load_bf8(qb + (size_t)c32 * DK + ks*16 + hi*8);

    f32x16 o[2];
    o[0] = zero16(); o[1] = zero16();
    float lrow = 0.f;

    for (int it = 0; it < SQ/64; ++it, kp += 64*DK, vp += 64){
        // issue K loads + first V half at top (overlap one memory wait)
        bf16x8 kf[2][4], vf[2][4];
        #pragma unroll
        for (int t = 0; t < 2; ++t)
            #pragma unroll
            for (int ks = 0; ks < 4; ++ks)
                kf[t][ks] = load_bf8(kp + t*32*DK + ks*16);
        #pragma unroll
        for (int f = 0; f < 4; ++f)
            vf[0][f] = load_bf8(vp + f*16);

        // QK^T: ks-outer, t-inner -> two independent accumulator chains interleave
        f32x16 sc[2];
        sc[0] = zero16(); sc[1] = zero16();
        __builtin_amdgcn_s_setprio(1);
        #pragma unroll
        for (int ks = 0; ks < 4; ++ks){
            sc[0] = __builtin_amdgcn_mfma_f32_32x32x16_bf16(kf[0][ks], qf[ks], sc[0], 0, 0, 0);
            sc[1] = __builtin_amdgcn_mfma_f32_32x32x16_bf16(kf[1][ks], qf[ks], sc[1], 0, 0, 0);
        }
        __builtin_amdgcn_s_setprio(0);

        // second V half: latency hides under exp2/pack
        #pragma unroll
        for (int f = 0; f < 4; ++f)
            vf[1][f] = load_bf8(vp + (size_t)32*SQ + f*16);

        // p = 2^sc, row-partial sums
        float ps[16];
        #pragma unroll
        for (int r = 0; r < 16; ++r){
            float p0 = exp2_hw(sc[0][r]);
            float p1 = exp2_hw(sc[1][r]);
            sc[0][r] = p0; sc[1][r] = p1;
            ps[r] = p0 + p1;
        }
        #pragma unroll
        for (int s = 8; s > 0; s >>= 1)
            #pragma unroll
            for (int r = 0; r < 8; ++r)
                if (r < s) ps[r] += ps[r + s];
        lrow += ps[0];

        // pack P to bf16 words: Wd[t][gq] covers kv rows t*32 + gq*8 + 4*hi .. +3
        unsigned Wd[2][4][2];
        #pragma unroll
        for (int t = 0; t < 2; ++t)
            #pragma unroll
            for (int gq = 0; gq < 4; ++gq){
                Wd[t][gq][0] = cvtpk(sc[t][gq*4+0], sc[t][gq*4+1]);
                Wd[t][gq][1] = cvtpk(sc[t][gq*4+2], sc[t][gq*4+3]);
            }
        // exchange complementary halves with lane^32
        unsigned Rv[2][2][2];
        #pragma unroll
        for (int t = 0; t < 2; ++t)
            #pragma unroll
            for (int gp = 0; gp < 2; ++gp)
                #pragma unroll
                for (int w = 0; w < 2; ++w){
                    unsigned snd = hi ? Wd[t][2*gp][w] : Wd[t][2*gp+1][w];
                    Rv[t][gp][w] = (unsigned)__shfl_xor((int)snd, 32, 64);
                }
        // assemble PV A-fragments: paf[f] holds P[q=c32][kv = f*16 + hi*8 + j]
        bf16x8 paf[4];
        #pragma unroll
        for (int t = 0; t < 2; ++t)
            #pragma unroll
            for (int gp = 0; gp < 2; ++gp){
                const int f = t*2 + gp;
                u32x4 wd;
                wd[0] = hi ? Rv[t][gp][0]     : Wd[t][2*gp][0];
                wd[1] = hi ? Rv[t][gp][1]     : Wd[t][2*gp][1];
                wd[2] = hi ? Wd[t][2*gp+1][0] : Rv[t][gp][0];
                wd[3] = hi ? Wd[t][2*gp+1][1] : Rv[t][gp][1];
                paf[f] = __builtin_bit_cast(bf16x8, wd);
            }

        // PV: f-outer, td-inner -> two independent chains interleave
        __builtin_amdgcn_s_setprio(1);
        #pragma unroll
        for (int f = 0; f < 4; ++f){
            o[0] = __builtin_amdgcn_mfma_f32_32x32x16_bf16(paf[f], vf[0][f], o[0], 0, 0, 0);
            o[1] = __builtin_amdgcn_mfma_f32_32x32x16_bf16(paf[f], vf[1][f], o[1], 0, 0, 0);
        }
        __builtin_amdgcn_s_setprio(0);
    }

    // finalize
    float ltot = lrow + __shfl_xor(lrow, 32, 64);
    float linv = 1.0f / ltot;
    float li[16];
    #pragma unroll
    for (int r = 0; r < 16; ++r)
        li[r] = __shfl(linv, (r&3) + 8*(r>>2) + 4*hi, 64);
    #pragma unroll
    for (int td = 0; td < 2; ++td)
        #pragma unroll
        for (int r = 0; r < 16; ++r){
            const int qrow = (r&3) + 8*(r>>2) + 4*hi;
            att[((size_t)(b*SQ + q0 + qrow)) * D_MODEL + h*DK + td*32 + c32] =
                f2bfu(o[td][r] * li[r]);
        }
}

extern "C" void kernel_launch(void* const* d_in, const int* in_sizes, int n_in,
                              void* d_out, int out_size, void* d_ws, size_t ws_size,
                              hipStream_t stream){
    const float* Q  = (const float*)d_in[0];
    const float* K  = (const float*)d_in[1];
    const float* V  = (const float*)d_in[2];
    const float* Wq = (const float*)d_in[3];
    const float* bq = (const float*)d_in[4];
    const float* Wk = (const float*)d_in[5];
    const float* bk = (const float*)d_in[6];
    const float* Wv = (const float*)d_in[7];
    const float* bv = (const float*)d_in[8];
    const float* Wo = (const float*)d_in[9];
    const float* bo = (const float*)d_in[10];
    float* out = (float*)d_out;

    unsigned short* q_ws   = (unsigned short*)d_ws;
    unsigned short* k_ws   = q_ws  + TENS_ELEMS;
    unsigned short* vt_ws  = k_ws  + TENS_ELEMS;
    unsigned short* att_ws = vt_ws + TENS_ELEMS;
    unsigned short* wbf    = att_ws + TENS_ELEMS;   // 4*WELEMS bf16
    unsigned short* xbf    = wbf + 4*WELEMS;        // XELEMS bf16 (reused 3x)

    wconv_kernel<<<dim3(576, 4), 256, 0, stream>>>(Wq, Wk, Wv, Wo, wbf);

    xconv_kernel<<<6144, 256, 0, stream>>>(Q, xbf);
    gemm_kernel<0><<<dim3(128, 12), 256, 0, stream>>>(xbf, wbf,            bq, QSCALE, q_ws);
    xconv_kernel<<<6144, 256, 0, stream>>>(K, xbf);
    gemm_kernel<1><<<dim3(128, 12), 256, 0, stream>>>(xbf, wbf + WELEMS,   bk, 1.0f,   k_ws);
    xconv_kernel<<<6144, 256, 0, stream>>>(V, xbf);
    gemm_kernel<2><<<dim3(128, 12), 256, 0, stream>>>(xbf, wbf + 2*WELEMS, bv, 1.0f,   vt_ws);

    attn_kernel<<<dim3(32, 24), 256, 0, stream>>>(q_ws, k_ws, vt_ws, att_ws);

    gemm_kernel<3><<<dim3(128, 12), 256, 0, stream>>>(att_ws, wbf + 3*WELEMS, bo, 1.0f, out);
}

// Round 9
// 689.397 us; speedup vs baseline: 1.1707x; 1.1707x over previous
//
#include <hip/hip_runtime.h>
#include <hip/hip_bf16.h>
#include <stdint.h>

#define D_MODEL 768
#define NHEAD 12
#define DK 64
#define SQ 4096
#define BATCH 2
#define MROWS (BATCH*SQ)                 // 8192
#define WELEMS (D_MODEL*D_MODEL)         // 589824
#define XELEMS ((size_t)MROWS*D_MODEL)   // 6291456
#define TENS_ELEMS ((size_t)BATCH*NHEAD*SQ*DK) // 6291456

// scale folded into q projection: (1/sqrt(dk)) * log2(e)
#define QSCALE 0.1803368801111244f

typedef __attribute__((ext_vector_type(8))) unsigned short u16x8;
typedef __attribute__((ext_vector_type(4))) unsigned short u16x4;
typedef __attribute__((ext_vector_type(4))) unsigned int   u32x4;
typedef __attribute__((ext_vector_type(8))) __bf16 bf16x8;
typedef __attribute__((ext_vector_type(4))) float f32x4;
typedef __attribute__((ext_vector_type(16))) float f32x16;

__device__ __forceinline__ unsigned short f2bfu(float f){
    uint32_t u = __float_as_uint(f);
    return (unsigned short)((u + 0x7fffu + ((u >> 16) & 1u)) >> 16);
}

__device__ __forceinline__ bf16x8 load_bf8(const unsigned short* p){
    u16x8 t = *reinterpret_cast<const u16x8*>(p);
    return __builtin_bit_cast(bf16x8, t);
}

__device__ __forceinline__ unsigned cvtpk(float lo, float hi){
    unsigned r;
    asm("v_cvt_pk_bf16_f32 %0, %1, %2" : "=v"(r) : "v"(lo), "v"(hi));
    return r;
}

// raw v_exp_f32: computes 2^x in one trans-pipe instruction (no libm expansion)
__device__ __forceinline__ float exp2_hw(float x){
    float r;
    asm("v_exp_f32 %0, %1" : "=v"(r) : "v"(x));
    return r;
}

__device__ __forceinline__ f32x16 zero16(){
    f32x16 z;
    #pragma unroll
    for (int i = 0; i < 16; ++i) z[i] = 0.f;
    return z;
}

// ---- weight convert: 4x (768x768) f32 -> bf16 packed [Wq|Wk|Wv|Wo] ----
__global__ __launch_bounds__(256) void wconv_kernel(const float* w0, const float* w1,
                                                    const float* w2, const float* w3,
                                                    unsigned short* dst){
    const float* src = (blockIdx.y == 0) ? w0 : (blockIdx.y == 1) ? w1 :
                       (blockIdx.y == 2) ? w2 : w3;
    unsigned short* d = dst + (size_t)blockIdx.y * WELEMS;
    int i = (blockIdx.x * blockDim.x + threadIdx.x) * 4;
    if (i < WELEMS){
        float4 v = *reinterpret_cast<const float4*>(src + i);
        u16x4 o;
        o[0]=f2bfu(v.x); o[1]=f2bfu(v.y); o[2]=f2bfu(v.z); o[3]=f2bfu(v.w);
        *reinterpret_cast<u16x4*>(d + i) = o;
    }
}

// ---- activation convert: 8192x768 f32 -> bf16 ----
__global__ __launch_bounds__(256) void xconv_kernel(const float* src, unsigned short* dst){
    size_t i = ((size_t)blockIdx.x * blockDim.x + threadIdx.x) * 4;
    float4 v = *reinterpret_cast<const float4*>(src + i);
    u16x4 o;
    o[0]=f2bfu(v.x); o[1]=f2bfu(v.y); o[2]=f2bfu(v.z); o[3]=f2bfu(v.w);
    *reinterpret_cast<u16x4*>(dst + i) = o;
}

// ---- Y = X @ W^T + b (scaled). A bf16 8192x768. Block 128x64, wave 32x64. ----
// (proven config: grid (64,12) = 768 blocks)
// MODE 0: out bf16 (B,H,S,dk) q (oscale=QSCALE)
// MODE 1: out bf16 (B,H,S,dk) k
// MODE 2: out bf16 (B,H,dk,S) v transposed
// MODE 3: out f32 row-major 8192x768
template<int MODE>
__global__ __launch_bounds__(256) void gemm_kernel(const unsigned short* A, const unsigned short* Wb,
                                                   const float* bias, float oscale, void* out_){
    const int wave = threadIdx.x >> 6, lane = threadIdx.x & 63;
    const int g = lane >> 4, c16 = lane & 15;
    const int m0 = blockIdx.x * 128 + wave * 32;
    const int n0 = blockIdx.y * 64;
    f32x4 acc[2][4];
    #pragma unroll
    for (int rt = 0; rt < 2; ++rt)
        #pragma unroll
        for (int c = 0; c < 4; ++c) acc[rt][c] = f32x4{0.f,0.f,0.f,0.f};
    for (int kc = 0; kc < D_MODEL; kc += 32){
        const int kk = kc + g * 8;
        bf16x8 a0 = load_bf8(A + (size_t)(m0 + c16) * D_MODEL + kk);
        bf16x8 a1 = load_bf8(A + (size_t)(m0 + 16 + c16) * D_MODEL + kk);
        #pragma unroll
        for (int c = 0; c < 4; ++c){
            bf16x8 bfr = load_bf8(Wb + (size_t)(n0 + c*16 + c16) * D_MODEL + kk);
            acc[0][c] = __builtin_amdgcn_mfma_f32_16x16x32_bf16(a0, bfr, acc[0][c], 0, 0, 0);
            acc[1][c] = __builtin_amdgcn_mfma_f32_16x16x32_bf16(a1, bfr, acc[1][c], 0, 0, 0);
        }
    }
    #pragma unroll
    for (int rt = 0; rt < 2; ++rt){
        #pragma unroll
        for (int c = 0; c < 4; ++c){
            const int n = n0 + c*16 + c16;
            const float bv = bias[n];
            #pragma unroll
            for (int r = 0; r < 4; ++r){
                const int mrow = m0 + rt*16 + g*4 + r;
                const float v = (acc[rt][c][r] + bv) * oscale;
                if constexpr (MODE == 3){
                    ((float*)out_)[(size_t)mrow * D_MODEL + n] = v;
                } else {
                    const int b = mrow >> 12, s = mrow & 4095;
                    const int h = n >> 6, d = n & 63;
                    unsigned short* o = (unsigned short*)out_;
                    if constexpr (MODE == 2){
                        o[((size_t)(b*NHEAD + h)*DK + d)*SQ + s] = f2bfu(v);
                    } else {
                        o[((size_t)(b*NHEAD + h)*SQ + s)*DK + d] = f2bfu(v);
                    }
                }
            }
        }
    }
}

// ---- Flash attention, swapped-QK^T 32x32, softmax fully in-register ----
// q (pre-scaled), k: (B,H,S,64) bf16. vt: (B,H,64,S) bf16. Out att: (B,S,768) bf16.
// Block = 4 waves x 32 q rows. KVBLK = 64. No max-subtraction (scores bounded).
// vs the r6-run PASSING version, the ONLY change is the block-index decode:
// 1D grid 768 with XCD pinning (xcd = L&7 under round-robin dispatch), 3 heads
// per XCD -> that XCD's L2 holds K+V (3MB < 4MB). Pure relabeling: each
// (bh, bq) block performs bit-identical work to the r6-run kernel.
// (kv stagger and __launch_bounds__(256,3) from the failed r8 run are REMOVED
//  pending bisection — one of them caused absmax 3.5e-2.)
__global__ __launch_bounds__(256) void attn_kernel(const unsigned short* q, const unsigned short* k,
                                                   const unsigned short* vt, unsigned short* att){
    const int lane = threadIdx.x & 63;
    const int wave = threadIdx.x >> 6;
    const int c32 = lane & 31, hi = lane >> 5;
    const int L = blockIdx.x;                 // 0..767
    const int xcd = L & 7, within = L >> 3;   // within: 0..95
    const int bh = xcd * 3 + (within >> 5);   // 3 heads per XCD, bijective
    const int bq = within & 31;               // q-block within head
    const int b = bh / NHEAD, h = bh - b * NHEAD;
    const int q0 = bq * 128 + wave * 32;
    const unsigned short* qb = q + ((size_t)bh * SQ + q0) * DK;

    // hoisted per-lane base pointers; inner offsets are compile-time immediates
    const unsigned short* kp = k  + (size_t)bh * SQ * DK + (size_t)c32 * DK + hi * 8;
    const unsigned short* vp = vt + (size_t)bh * DK * SQ + (size_t)c32 * SQ + hi * 8;

    bf16x8 qf[4];
    #pragma unroll
    for (int ks = 0; ks < 4; ++ks)
        qf[ks] = load_bf8(qb + (size_t)c32 * DK + ks*16 + hi*8);

    f32x16 o[2];
    o[0] = zero16(); o[1] = zero16();
    float lrow = 0.f;

    for (int it = 0; it < SQ/64; ++it, kp += 64*DK, vp += 64){
        // issue K loads + first V half at top (overlap one memory wait)
        bf16x8 kf[2][4], vf[2][4];
        #pragma unroll
        for (int t = 0; t < 2; ++t)
            #pragma unroll
            for (int ks = 0; ks < 4; ++ks)
                kf[t][ks] = load_bf8(kp + t*32*DK + ks*16);
        #pragma unroll
        for (int f = 0; f < 4; ++f)
            vf[0][f] = load_bf8(vp + f*16);

        // QK^T: two independent accumulator chains interleave
        f32x16 sc[2];
        sc[0] = zero16(); sc[1] = zero16();
        __builtin_amdgcn_s_setprio(1);
        #pragma unroll
        for (int ks = 0; ks < 4; ++ks){
            sc[0] = __builtin_amdgcn_mfma_f32_32x32x16_bf16(kf[0][ks], qf[ks], sc[0], 0, 0, 0);
            sc[1] = __builtin_amdgcn_mfma_f32_32x32x16_bf16(kf[1][ks], qf[ks], sc[1], 0, 0, 0);
        }
        __builtin_amdgcn_s_setprio(0);

        // second V half: latency hides under exp2/pack
        #pragma unroll
        for (int f = 0; f < 4; ++f)
            vf[1][f] = load_bf8(vp + (size_t)32*SQ + f*16);

        // p = 2^sc, row-partial sums
        float ps[16];
        #pragma unroll
        for (int r = 0; r < 16; ++r){
            float p0 = exp2_hw(sc[0][r]);
            float p1 = exp2_hw(sc[1][r]);
            sc[0][r] = p0; sc[1][r] = p1;
            ps[r] = p0 + p1;
        }
        #pragma unroll
        for (int s = 8; s > 0; s >>= 1)
            #pragma unroll
            for (int r = 0; r < 8; ++r)
                if (r < s) ps[r] += ps[r + s];
        lrow += ps[0];

        // pack P to bf16 words: Wd[t][gq] covers kv rows t*32 + gq*8 + 4*hi .. +3
        unsigned Wd[2][4][2];
        #pragma unroll
        for (int t = 0; t < 2; ++t)
            #pragma unroll
            for (int gq = 0; gq < 4; ++gq){
                Wd[t][gq][0] = cvtpk(sc[t][gq*4+0], sc[t][gq*4+1]);
                Wd[t][gq][1] = cvtpk(sc[t][gq*4+2], sc[t][gq*4+3]);
            }
        // exchange complementary halves with lane^32
        unsigned Rv[2][2][2];
        #pragma unroll
        for (int t = 0; t < 2; ++t)
            #pragma unroll
            for (int gp = 0; gp < 2; ++gp)
                #pragma unroll
                for (int w = 0; w < 2; ++w){
                    unsigned snd = hi ? Wd[t][2*gp][w] : Wd[t][2*gp+1][w];
                    Rv[t][gp][w] = (unsigned)__shfl_xor((int)snd, 32, 64);
                }
        // assemble PV A-fragments: paf[f] holds P[q=c32][kv = f*16 + hi*8 + j]
        bf16x8 paf[4];
        #pragma unroll
        for (int t = 0; t < 2; ++t)
            #pragma unroll
            for (int gp = 0; gp < 2; ++gp){
                const int f = t*2 + gp;
                u32x4 wd;
                wd[0] = hi ? Rv[t][gp][0]     : Wd[t][2*gp][0];
                wd[1] = hi ? Rv[t][gp][1]     : Wd[t][2*gp][1];
                wd[2] = hi ? Wd[t][2*gp+1][0] : Rv[t][gp][0];
                wd[3] = hi ? Wd[t][2*gp+1][1] : Rv[t][gp][1];
                paf[f] = __builtin_bit_cast(bf16x8, wd);
            }

        // PV: two independent chains interleave
        __builtin_amdgcn_s_setprio(1);
        #pragma unroll
        for (int f = 0; f < 4; ++f){
            o[0] = __builtin_amdgcn_mfma_f32_32x32x16_bf16(paf[f], vf[0][f], o[0], 0, 0, 0);
            o[1] = __builtin_amdgcn_mfma_f32_32x32x16_bf16(paf[f], vf[1][f], o[1], 0, 0, 0);
        }
        __builtin_amdgcn_s_setprio(0);
    }

    // finalize
    float ltot = lrow + __shfl_xor(lrow, 32, 64);
    float linv = 1.0f / ltot;
    float li[16];
    #pragma unroll
    for (int r = 0; r < 16; ++r)
        li[r] = __shfl(linv, (r&3) + 8*(r>>2) + 4*hi, 64);
    #pragma unroll
    for (int td = 0; td < 2; ++td)
        #pragma unroll
        for (int r = 0; r < 16; ++r){
            const int qrow = (r&3) + 8*(r>>2) + 4*hi;
            att[((size_t)(b*SQ + q0 + qrow)) * D_MODEL + h*DK + td*32 + c32] =
                f2bfu(o[td][r] * li[r]);
        }
}

extern "C" void kernel_launch(void* const* d_in, const int* in_sizes, int n_in,
                              void* d_out, int out_size, void* d_ws, size_t ws_size,
                              hipStream_t stream){
    const float* Q  = (const float*)d_in[0];
    const float* K  = (const float*)d_in[1];
    const float* V  = (const float*)d_in[2];
    const float* Wq = (const float*)d_in[3];
    const float* bq = (const float*)d_in[4];
    const float* Wk = (const float*)d_in[5];
    const float* bk = (const float*)d_in[6];
    const float* Wv = (const float*)d_in[7];
    const float* bv = (const float*)d_in[8];
    const float* Wo = (const float*)d_in[9];
    const float* bo = (const float*)d_in[10];
    float* out = (float*)d_out;

    unsigned short* q_ws   = (unsigned short*)d_ws;
    unsigned short* k_ws   = q_ws  + TENS_ELEMS;
    unsigned short* vt_ws  = k_ws  + TENS_ELEMS;
    unsigned short* att_ws = vt_ws + TENS_ELEMS;
    unsigned short* wbf    = att_ws + TENS_ELEMS;   // 4*WELEMS bf16
    unsigned short* xbf    = wbf + 4*WELEMS;        // XELEMS bf16 (reused 3x)

    wconv_kernel<<<dim3(576, 4), 256, 0, stream>>>(Wq, Wk, Wv, Wo, wbf);

    xconv_kernel<<<6144, 256, 0, stream>>>(Q, xbf);
    gemm_kernel<0><<<dim3(64, 12), 256, 0, stream>>>(xbf, wbf,            bq, QSCALE, q_ws);
    xconv_kernel<<<6144, 256, 0, stream>>>(K, xbf);
    gemm_kernel<1><<<dim3(64, 12), 256, 0, stream>>>(xbf, wbf + WELEMS,   bk, 1.0f,   k_ws);
    xconv_kernel<<<6144, 256, 0, stream>>>(V, xbf);
    gemm_kernel<2><<<dim3(64, 12), 256, 0, stream>>>(xbf, wbf + 2*WELEMS, bv, 1.0f,   vt_ws);

    attn_kernel<<<768, 256, 0, stream>>>(q_ws, k_ws, vt_ws, att_ws);

    gemm_kernel<3><<<dim3(64, 12), 256, 0, stream>>>(att_ws, wbf + 3*WELEMS, bo, 1.0f, out);
}